// Round 7
// baseline (6768.261 us; speedup 1.0000x reference)
//
#include <hip/hip_runtime.h>
#include <hip/hip_bf16.h>

#define RES 64
#define WIDTH 32
#define MODES 8
#define R3 262144            // 64^3
#define TWO_PI_OVER_64 0.09817477042468103f

__device__ __forceinline__ float geluf(float x) {
    // jax.nn.gelu approximate=True: x * sigmoid(1.595769...*(x+0.044715x^3))
    float g = 1.5957691216057308f * (x + 0.044715f * x * x * x);
    return x / (1.0f + __expf(-g));
}

// ---------------- K0: fc0 pointwise (3 -> 32) ----------------
__global__ void k_fc0(const float* __restrict__ u, const float* __restrict__ w,
                      const float* __restrict__ bias, float* __restrict__ X) {
    __shared__ float ws[96];
    __shared__ float bs[32];
    int t = threadIdx.x;
    if (t < 96) ws[t] = w[t];
    if (t < 32) bs[t] = bias[t];
    __syncthreads();
    size_t s = (size_t)blockIdx.x * 256 + t;     // over B*R3 = 1048576
    int b = (int)(s >> 18);
    size_t p = s & (R3 - 1);
    const float* ub = u + (size_t)b * 3 * R3;
    float u0 = ub[p], u1 = ub[R3 + p], u2 = ub[2 * R3 + p];
    float* xb = X + (size_t)b * 32 * R3;
    #pragma unroll
    for (int o = 0; o < 32; o++) {
        xb[(size_t)o * R3 + p] = bs[o] + u0 * ws[o] + u1 * ws[32 + o] + u2 * ws[64 + o];
    }
}

// ---------------- K1: fused forward DFT over z (64->8) and y (64->16 bins) ----------------
// block per (bc, x): 8192 blocks, 256 threads
__global__ void k_fwd_zy(const float* __restrict__ X, float2* __restrict__ S2) {
    int blk = blockIdx.x;                 // bc*64 + x
    int t = threadIdx.x;
    __shared__ float xt[4096];            // [y][z] plane, 16 KB
    __shared__ float2 zt[512];            // [y][kz]
    __shared__ float2 tw[64];
    if (t < 64) { float s, c; __sincosf(TWO_PI_OVER_64 * t, &s, &c); tw[t] = make_float2(c, s); }
    const float4* src = (const float4*)(X + (size_t)blk * 4096);
    #pragma unroll
    for (int i = 0; i < 4; i++) ((float4*)xt)[t + 256 * i] = src[t + 256 * i];
    __syncthreads();
    // z-DFT: 512 outputs (y,k), 2 per thread
    #pragma unroll
    for (int half = 0; half < 2; half++) {
        int e = t + 256 * half;
        int y = e >> 3, k = e & 7;
        float re = 0.f, im = 0.f;
        const float* row = xt + y * 64;
        #pragma unroll 8
        for (int z = 0; z < 64; z++) {
            float v = row[z];
            float2 w = tw[(k * z) & 63];
            re += v * w.x;
            im -= v * w.y;
        }
        zt[e] = make_float2(re, im);
    }
    __syncthreads();
    // y-DFT: 128 outputs (jy,k)
    if (t < 128) {
        int jy = t >> 3, k = t & 7;
        int f = jy < 8 ? jy : 48 + jy;
        float re = 0.f, im = 0.f;
        #pragma unroll 8
        for (int y = 0; y < 64; y++) {
            float2 v = zt[y * 8 + k];
            float2 w = tw[(f * y) & 63];
            re += v.x * w.x + v.y * w.y;   // * conj(w)
            im += v.y * w.x - v.x * w.y;
        }
        S2[(size_t)blk * 128 + t] = make_float2(re, im);
    }
}

// ---------------- K2: forward DFT over x: 64 -> 16 bins ----------------
// block per (bc, kz); 1024 blocks, 256 threads (jx16 x jy16)
__global__ void k_fwd_x(const float2* __restrict__ S2, float2* __restrict__ S3) {
    int bc = blockIdx.x >> 3, kz = blockIdx.x & 7;
    int t = threadIdx.x;
    __shared__ float2 in[64 * 16];  // [x][jy]
    __shared__ float2 tw[64];
    if (t < 64) { float s, c; __sincosf(TWO_PI_OVER_64 * t, &s, &c); tw[t] = make_float2(c, s); }
    #pragma unroll
    for (int i = 0; i < 4; i++) {
        int e = t + 256 * i;        // e = x*16 + jy
        in[e] = S2[((size_t)bc * 1024 + e) * 8 + kz];
    }
    __syncthreads();
    int jx = t >> 4, jy = t & 15;
    int f = jx < 8 ? jx : 48 + jx;
    float re = 0.f, im = 0.f;
    for (int x = 0; x < 64; x++) {
        float2 v = in[x * 16 + jy];
        float2 w = tw[(f * x) & 63];
        re += v.x * w.x + v.y * w.y;
        im += v.y * w.x - v.x * w.y;
    }
    // S3 layout: [b][i][mode], mode = (jx*16+jy)*8 + kz
    S3[(size_t)bc * 2048 + (size_t)t * 8 + kz] = make_float2(re, im);
}

// ---------------- K3: spectral multiply, two m3-modes per block ----------------
// out[b,o,mode] = sum_i in[b,i,mode]*W[i,o]; 1024 blocks, 128 threads (b4 x o32)
__global__ void k_specmul(const float2* __restrict__ S3, const float* __restrict__ spec_w,
                          float2* __restrict__ S4, int layer) {
    int mp = blockIdx.x;                 // mode pair
    int t = threadIdx.x;
    int jxy = mp >> 2;                   // jx*16+jy
    int kz0 = (mp & 3) * 2;
    int jy = jxy & 15, jx = jxy >> 4;
    int corner = (jx >= 8 ? 1 : 0) + (jy >= 8 ? 2 : 0);
    int m1 = jx & 7, m2 = jy & 7;
    int mode0 = jxy * 8 + kz0;
    __shared__ float4 W4[1024];          // [i][o] -> (re0,im0,re1,im1)
    __shared__ float2 inb[2][128];       // [mode][b*32+i]
    const float* wbase = spec_w + (size_t)layer * 4194304 + (size_t)corner * 1048576
                       + m1 * 128 + m2 * 16 + kz0 * 2;
    #pragma unroll
    for (int j = 0; j < 8; j++) {
        int e = t + 128 * j;    // i*32 + o
        int i = e >> 5, o = e & 31;
        W4[e] = *(const float4*)(wbase + (size_t)i * 32768 + (size_t)o * 1024);
    }
    inb[0][t] = S3[(size_t)t * 2048 + mode0];
    inb[1][t] = S3[(size_t)t * 2048 + mode0 + 1];
    __syncthreads();
    int b = t >> 5, o = t & 31;
    float re0 = 0.f, im0 = 0.f, re1 = 0.f, im1 = 0.f;
    #pragma unroll 8
    for (int i = 0; i < 32; i++) {
        float2 a0 = inb[0][b * 32 + i];
        float2 a1 = inb[1][b * 32 + i];
        float4 w = W4[i * 32 + o];
        re0 += a0.x * w.x - a0.y * w.y;
        im0 += a0.x * w.y + a0.y * w.x;
        re1 += a1.x * w.z - a1.y * w.w;
        im1 += a1.x * w.w + a1.y * w.z;
    }
    S4[(size_t)(b * 32 + o) * 2048 + mode0]     = make_float2(re0, im0);
    S4[(size_t)(b * 32 + o) * 2048 + mode0 + 1] = make_float2(re1, im1);
}

// ---------------- K4: inverse DFT over x: 16 bins -> 64 ----------------
// block per (bo, kz); 1024 blocks, 256 threads
__global__ void k_inv_x(const float2* __restrict__ S4, float2* __restrict__ S5) {
    int bo = blockIdx.x >> 3, kz = blockIdx.x & 7;
    int t = threadIdx.x;
    __shared__ float2 in[256];   // [jx][jy]
    __shared__ float2 tw[64];
    if (t < 64) { float s, c; __sincosf(TWO_PI_OVER_64 * t, &s, &c); tw[t] = make_float2(c, s); }
    in[t] = S4[(size_t)bo * 2048 + (size_t)t * 8 + kz];
    __syncthreads();
    int x = t & 63, g = t >> 6;
    #pragma unroll
    for (int m = 0; m < 4; m++) {
        int jy = g + 4 * m;
        float re = 0.f, im = 0.f;
        #pragma unroll
        for (int jx = 0; jx < 16; jx++) {
            int f = jx < 8 ? jx : 48 + jx;
            float2 v = in[jx * 16 + jy];
            float2 w = tw[(f * x) & 63];
            re += v.x * w.x - v.y * w.y;   // e^{+i theta}
            im += v.x * w.y + v.y * w.x;
        }
        // S5 layout [bo][x][jy][kz]
        S5[((size_t)bo * 64 + x) * 128 + jy * 8 + kz] = make_float2(re, im);
    }
}

// ---------------- K5: fused inverse-y + inverse-z DFT + pointwise + add + gelu (IN-PLACE on X) ----
// block per (b, x, ygroup of 16): 1024 blocks, 256 threads
// r6 shape, with stage-C LDS-issue reduction:
//  - twr[8] z-twiddles are PLAIN COPIES from the LDS tw table, loaded once per block.
//    (r3/r4/r5 used __sincosf writing into the local array -> array forced to scratch ->
//     GBs of HBM scratch traffic. Never sincos into a local array.)
//  - c-outer pointwise with acc[8]: xt read once per c (32 reads/y vs 256).
//  - wt read as two broadcast float4 per c (64 b128 broadcasts vs 256 b32).
__global__ void __launch_bounds__(256, 3)
k_inv_yz_pw(const float2* __restrict__ S5, const float* __restrict__ w_pw,
            const float* __restrict__ b_pw, float* __restrict__ X,
            int layer, int do_gelu) {
    int blk = blockIdx.x;
    int yg = blk & 3, x = (blk >> 2) & 63, b = blk >> 8;
    int t = threadIdx.x;
    __shared__ float2 s5s[32 * 132];   // [o][jy*8+k], padded rows  33792 B
    __shared__ float2 st[256];         // [o][k]        2 KB
    __shared__ float xt[2048];         // [c][z]        8 KB
    __shared__ float wt[1024];         // w_pw [c][o]   4 KB
    __shared__ float bt[32];
    __shared__ float2 tw[64];
    if (t < 64) { float s, c; __sincosf(TWO_PI_OVER_64 * t, &s, &c); tw[t] = make_float2(c, s); }
    // stage s5s: coalesced float4 loads (per o: 128 contiguous float2), padded store
    #pragma unroll
    for (int i = 0; i < 8; i++) {
        int f4 = t + 256 * i;          // [0,2048): o*64 + j4
        int o = f4 >> 6, j4 = f4 & 63;
        float4 v = ((const float4*)(S5 + ((size_t)(b * 32 + o) * 64 + x) * 128))[j4];
        *(float4*)(&s5s[o * 132 + j4 * 2]) = v;
    }
    #pragma unroll
    for (int i = t; i < 1024; i += 256) wt[i] = w_pw[layer * 1024 + i];
    if (t < 32) bt[t] = b_pw[layer * 32 + t];
    __syncthreads();
    int z = t & 63, og = t >> 6;
    // z-twiddles in registers: plain LDS copies (NOT sincos-into-array)
    float2 twr[8];
    #pragma unroll
    for (int k = 0; k < 8; k++) twr[k] = tw[(k * z) & 63];
    const float inv_n = 1.0f / 262144.0f;
    for (int yi = 0; yi < 16; yi++) {
        int y = yg * 16 + yi;
        // stage A: inverse-y for this y -> st[o][k]; padded s5s rows
        {
            int o = t >> 3, k = t & 7;
            float re = 0.f, im = 0.f;
            #pragma unroll
            for (int jy = 0; jy < 16; jy++) {
                int f = jy < 8 ? jy : 48 + jy;
                float2 v = s5s[o * 132 + jy * 8 + k];
                float2 w = tw[(f * y) & 63];
                re += v.x * w.x - v.y * w.y;   // e^{+i theta}
                im += v.x * w.y + v.y * w.x;
            }
            st[t] = make_float2(re, im);
        }
        // stage B: load X column for this y
        size_t base = (size_t)b * 8388608 + (size_t)(x * 64 + y) * 64;
        #pragma unroll
        for (int i = 0; i < 8; i++) {
            int e = t + 256 * i;   // c*64 + z
            int c = e >> 6, zz = e & 63;
            xt[e] = X[base + (size_t)c * R3 + zz];
        }
        __syncthreads();
        // stage C init: inverse-z (pocketfft c2r: Re of k=0, 2x k=1..7) from st broadcasts
        float acc[8];
        #pragma unroll
        for (int oi = 0; oi < 8; oi++) {
            int o = og * 8 + oi;
            float s = 0.f;
            #pragma unroll
            for (int k = 0; k < 8; k++) {
                float2 v = st[o * 8 + k];          // wave-uniform: LDS broadcast
                float term = v.x * twr[k].x - v.y * twr[k].y;
                s += (k == 0) ? term : 2.f * term;
            }
            acc[oi] = bt[o] + s * inv_n;
        }
        // stage C main: c-outer pointwise, xt read once per c, wt broadcast float4
        #pragma unroll
        for (int c = 0; c < 32; c++) {
            float xc = xt[c * 64 + z];
            const float4 w0 = *(const float4*)(wt + c * 32 + og * 8);      // broadcast
            const float4 w1 = *(const float4*)(wt + c * 32 + og * 8 + 4);  // broadcast
            acc[0] += xc * w0.x; acc[1] += xc * w0.y;
            acc[2] += xc * w0.z; acc[3] += xc * w0.w;
            acc[4] += xc * w1.x; acc[5] += xc * w1.y;
            acc[6] += xc * w1.z; acc[7] += xc * w1.w;
        }
        __syncthreads();   // all st/xt reads done before next iteration overwrites
        #pragma unroll
        for (int oi = 0; oi < 8; oi++) {
            float r = do_gelu ? geluf(acc[oi]) : acc[oi];
            X[base + (size_t)(og * 8 + oi) * R3 + z] = r;
        }
    }
}

// ---------------- K6: head fc1(32->128) + gelu + fc2(128->6), scalar-pipe weights ----------------
// 4096 blocks, 256 threads, one site each
__global__ void k_head(const float* __restrict__ X, const float* __restrict__ w1,
                       const float* __restrict__ b1, const float* __restrict__ w2,
                       const float* __restrict__ b2, float* __restrict__ tau_out) {
    int t = threadIdx.x;
    size_t s = (size_t)blockIdx.x * 256 + t;
    int b = (int)(s >> 18);
    size_t p = s & (R3 - 1);
    float xr[32];
    const float* xb = X + (size_t)b * 8388608 + p;
    #pragma unroll
    for (int c = 0; c < 32; c++) xr[c] = xb[(size_t)c * R3];
    float acc[6];
    #pragma unroll
    for (int o = 0; o < 6; o++) acc[o] = b2[o];
    for (int h = 0; h < 128; h += 4) {
        float a0 = b1[h], a1 = b1[h + 1], a2 = b1[h + 2], a3 = b1[h + 3];
        #pragma unroll
        for (int c = 0; c < 32; c++) {
            float xv = xr[c];
            const float* wr = w1 + c * 128 + h;   // uniform: s_load_dwordx4
            a0 += xv * wr[0];
            a1 += xv * wr[1];
            a2 += xv * wr[2];
            a3 += xv * wr[3];
        }
        a0 = geluf(a0); a1 = geluf(a1); a2 = geluf(a2); a3 = geluf(a3);
        const float* w2r = w2 + h * 6;            // uniform: 24 contiguous floats
        #pragma unroll
        for (int o = 0; o < 6; o++) {
            acc[o] += a0 * w2r[o] + a1 * w2r[6 + o] + a2 * w2r[12 + o] + a3 * w2r[18 + o];
        }
    }
    float* ob = tau_out + (size_t)b * 6 * R3 + p;
    #pragma unroll
    for (int o = 0; o < 6; o++) ob[(size_t)o * R3] = acc[o];
}

// ---------------- K7: NS hard core + combine ----------------
// 12288 blocks, 256 threads; s over B*3*R3
__global__ void k_hard(const float* __restrict__ u, const float* __restrict__ tau,
                       float* __restrict__ out0) {
    size_t s = (size_t)blockIdx.x * 256 + threadIdx.x;
    int bi = (int)(s >> 18);
    int b = bi / 3, i = bi % 3;
    size_t p = s & (R3 - 1);
    int x = (int)(p >> 12), y = ((int)p >> 6) & 63, z = (int)p & 63;
    const float dx = TWO_PI_OVER_64;
    const float inv2dx = 1.0f / (2.0f * dx);
    const float invdx2 = 1.0f / (dx * dx);
    const float* ub = u + (size_t)b * 3 * R3;
    const float* ui = ub + (size_t)i * R3;
    int xp = (x + 1) & 63, xm = (x + 63) & 63;
    int yp = (y + 1) & 63, ym = (y + 63) & 63;
    int zp = (z + 1) & 63, zm = (z + 63) & 63;
    float c0 = ui[p];
    float upx = ui[((size_t)xp << 12) | (y << 6) | z], umx = ui[((size_t)xm << 12) | (y << 6) | z];
    float upy = ui[((size_t)x << 12) | (yp << 6) | z], umy = ui[((size_t)x << 12) | (ym << 6) | z];
    float upz = ui[((size_t)x << 12) | (y << 6) | zp], umz = ui[((size_t)x << 12) | (y << 6) | zm];
    float u0c = ub[p], u1c = ub[R3 + p], u2c = ub[2 * R3 + p];
    float conv = -(u0c * (upx - umx) + u1c * (upy - umy) + u2c * (upz - umz)) * inv2dx;
    float diff = (upx + umx + upy + umy + upz + umz - 6.0f * c0) * invdx2;
    float tauv = tau[(size_t)b * 6 * R3 + (size_t)i * R3 + p];
    out0[s] = conv + 0.000185f * diff + 0.001f * tauv;
}

extern "C" void kernel_launch(void* const* d_in, const int* in_sizes, int n_in,
                              void* d_out, int out_size, void* d_ws, size_t ws_size,
                              hipStream_t stream) {
    const float* u      = (const float*)d_in[0];
    const float* fc0_w  = (const float*)d_in[1];
    const float* fc0_b  = (const float*)d_in[2];
    const float* spec_w = (const float*)d_in[3];
    const float* w_pw   = (const float*)d_in[4];
    const float* b_pw   = (const float*)d_in[5];
    const float* fc1_w  = (const float*)d_in[6];
    const float* fc1_b  = (const float*)d_in[7];
    const float* fc2_w  = (const float*)d_in[8];
    const float* fc2_b  = (const float*)d_in[9];
    float* out = (float*)d_out;

    // d_ws: only the activation tensor X (B*32*64^3 floats = 128 MiB), updated in place.
    float* X = (float*)d_ws;

    // Spectral stage buffers live in d_out's dead space (20 MiB of 36 MiB total).
    // All are dead before k_head/k_hard overwrite tau/du at the end.
    float2* S2 = (float2*)(out);                // 1048576 float2 =  8 MiB, floats [0, 2097152)
    float2* S3 = (float2*)(out + 2097152);      //  262144 float2 =  2 MiB
    float2* S4 = (float2*)(out + 2621440);      //  262144 float2 =  2 MiB
    float2* S5 = (float2*)(out + 3145728);      // 1048576 float2 =  8 MiB, ends at float 5242880

    k_fc0<<<4096, 256, 0, stream>>>(u, fc0_w, fc0_b, X);

    for (int l = 0; l < 4; l++) {
        k_fwd_zy<<<8192, 256, 0, stream>>>(X, S2);
        k_fwd_x<<<1024, 256, 0, stream>>>(S2, S3);
        k_specmul<<<1024, 128, 0, stream>>>(S3, spec_w, S4, l);
        k_inv_x<<<1024, 256, 0, stream>>>(S4, S5);
        k_inv_yz_pw<<<1024, 256, 0, stream>>>(S5, w_pw, b_pw, X, l, (l < 3) ? 1 : 0);
    }

    float* tau_out = out + (size_t)4 * 3 * R3;   // second output section (offset 3145728)
    k_head<<<4096, 256, 0, stream>>>(X, fc1_w, fc1_b, fc2_w, fc2_b, tau_out);
    k_hard<<<12288, 256, 0, stream>>>(u, tau_out, out);
}

// Round 8
// 1393.306 us; speedup vs baseline: 4.8577x; 4.8577x over previous
//
#include <hip/hip_runtime.h>
#include <hip/hip_bf16.h>

#define RES 64
#define WIDTH 32
#define MODES 8
#define R3 262144            // 64^3
#define TWO_PI_OVER_64 0.09817477042468103f

__device__ __forceinline__ float geluf(float x) {
    // jax.nn.gelu approximate=True: x * sigmoid(1.595769...*(x+0.044715x^3))
    float g = 1.5957691216057308f * (x + 0.044715f * x * x * x);
    return x / (1.0f + __expf(-g));
}

// ---------------- K0: fc0 pointwise (3 -> 32) ----------------
__global__ void k_fc0(const float* __restrict__ u, const float* __restrict__ w,
                      const float* __restrict__ bias, float* __restrict__ X) {
    __shared__ float ws[96];
    __shared__ float bs[32];
    int t = threadIdx.x;
    if (t < 96) ws[t] = w[t];
    if (t < 32) bs[t] = bias[t];
    __syncthreads();
    size_t s = (size_t)blockIdx.x * 256 + t;     // over B*R3 = 1048576
    int b = (int)(s >> 18);
    size_t p = s & (R3 - 1);
    const float* ub = u + (size_t)b * 3 * R3;
    float u0 = ub[p], u1 = ub[R3 + p], u2 = ub[2 * R3 + p];
    float* xb = X + (size_t)b * 32 * R3;
    #pragma unroll
    for (int o = 0; o < 32; o++) {
        xb[(size_t)o * R3 + p] = bs[o] + u0 * ws[o] + u1 * ws[32 + o] + u2 * ws[64 + o];
    }
}

// ---------------- K1: fused forward DFT over z (64->8) and y (64->16 bins) ----------------
// block per (bc, x): 8192 blocks, 256 threads
__global__ void k_fwd_zy(const float* __restrict__ X, float2* __restrict__ S2) {
    int blk = blockIdx.x;                 // bc*64 + x
    int t = threadIdx.x;
    __shared__ float xt[4096];            // [y][z] plane, 16 KB
    __shared__ float2 zt[512];            // [y][kz]
    __shared__ float2 tw[64];
    if (t < 64) { float s, c; __sincosf(TWO_PI_OVER_64 * t, &s, &c); tw[t] = make_float2(c, s); }
    const float4* src = (const float4*)(X + (size_t)blk * 4096);
    #pragma unroll
    for (int i = 0; i < 4; i++) ((float4*)xt)[t + 256 * i] = src[t + 256 * i];
    __syncthreads();
    // z-DFT: 512 outputs (y,k), 2 per thread
    #pragma unroll
    for (int half = 0; half < 2; half++) {
        int e = t + 256 * half;
        int y = e >> 3, k = e & 7;
        float re = 0.f, im = 0.f;
        const float* row = xt + y * 64;
        #pragma unroll 8
        for (int z = 0; z < 64; z++) {
            float v = row[z];
            float2 w = tw[(k * z) & 63];
            re += v * w.x;
            im -= v * w.y;
        }
        zt[e] = make_float2(re, im);
    }
    __syncthreads();
    // y-DFT: 128 outputs (jy,k)
    if (t < 128) {
        int jy = t >> 3, k = t & 7;
        int f = jy < 8 ? jy : 48 + jy;
        float re = 0.f, im = 0.f;
        #pragma unroll 8
        for (int y = 0; y < 64; y++) {
            float2 v = zt[y * 8 + k];
            float2 w = tw[(f * y) & 63];
            re += v.x * w.x + v.y * w.y;   // * conj(w)
            im += v.y * w.x - v.x * w.y;
        }
        S2[(size_t)blk * 128 + t] = make_float2(re, im);
    }
}

// ---------------- K2: forward DFT over x: 64 -> 16 bins ----------------
// block per (bc, kz); 1024 blocks, 256 threads (jx16 x jy16)
__global__ void k_fwd_x(const float2* __restrict__ S2, float2* __restrict__ S3) {
    int bc = blockIdx.x >> 3, kz = blockIdx.x & 7;
    int t = threadIdx.x;
    __shared__ float2 in[64 * 16];  // [x][jy]
    __shared__ float2 tw[64];
    if (t < 64) { float s, c; __sincosf(TWO_PI_OVER_64 * t, &s, &c); tw[t] = make_float2(c, s); }
    #pragma unroll
    for (int i = 0; i < 4; i++) {
        int e = t + 256 * i;        // e = x*16 + jy
        in[e] = S2[((size_t)bc * 1024 + e) * 8 + kz];
    }
    __syncthreads();
    int jx = t >> 4, jy = t & 15;
    int f = jx < 8 ? jx : 48 + jx;
    float re = 0.f, im = 0.f;
    for (int x = 0; x < 64; x++) {
        float2 v = in[x * 16 + jy];
        float2 w = tw[(f * x) & 63];
        re += v.x * w.x + v.y * w.y;
        im += v.y * w.x - v.x * w.y;
    }
    // S3 layout: [b][i][mode], mode = (jx*16+jy)*8 + kz
    S3[(size_t)bc * 2048 + (size_t)t * 8 + kz] = make_float2(re, im);
}

// ---------------- K3: spectral multiply, two m3-modes per block ----------------
// out[b,o,mode] = sum_i in[b,i,mode]*W[i,o]; 1024 blocks, 128 threads (b4 x o32)
__global__ void k_specmul(const float2* __restrict__ S3, const float* __restrict__ spec_w,
                          float2* __restrict__ S4, int layer) {
    int mp = blockIdx.x;                 // mode pair
    int t = threadIdx.x;
    int jxy = mp >> 2;                   // jx*16+jy
    int kz0 = (mp & 3) * 2;
    int jy = jxy & 15, jx = jxy >> 4;
    int corner = (jx >= 8 ? 1 : 0) + (jy >= 8 ? 2 : 0);
    int m1 = jx & 7, m2 = jy & 7;
    int mode0 = jxy * 8 + kz0;
    __shared__ float4 W4[1024];          // [i][o] -> (re0,im0,re1,im1)
    __shared__ float2 inb[2][128];       // [mode][b*32+i]
    const float* wbase = spec_w + (size_t)layer * 4194304 + (size_t)corner * 1048576
                       + m1 * 128 + m2 * 16 + kz0 * 2;
    #pragma unroll
    for (int j = 0; j < 8; j++) {
        int e = t + 128 * j;    // i*32 + o
        int i = e >> 5, o = e & 31;
        W4[e] = *(const float4*)(wbase + (size_t)i * 32768 + (size_t)o * 1024);
    }
    inb[0][t] = S3[(size_t)t * 2048 + mode0];
    inb[1][t] = S3[(size_t)t * 2048 + mode0 + 1];
    __syncthreads();
    int b = t >> 5, o = t & 31;
    float re0 = 0.f, im0 = 0.f, re1 = 0.f, im1 = 0.f;
    #pragma unroll 8
    for (int i = 0; i < 32; i++) {
        float2 a0 = inb[0][b * 32 + i];
        float2 a1 = inb[1][b * 32 + i];
        float4 w = W4[i * 32 + o];
        re0 += a0.x * w.x - a0.y * w.y;
        im0 += a0.x * w.y + a0.y * w.x;
        re1 += a1.x * w.z - a1.y * w.w;
        im1 += a1.x * w.w + a1.y * w.z;
    }
    S4[(size_t)(b * 32 + o) * 2048 + mode0]     = make_float2(re0, im0);
    S4[(size_t)(b * 32 + o) * 2048 + mode0 + 1] = make_float2(re1, im1);
}

// ---------------- K4: inverse DFT over x: 16 bins -> 64 ----------------
// block per (bo, kz); 1024 blocks, 256 threads
__global__ void k_inv_x(const float2* __restrict__ S4, float2* __restrict__ S5) {
    int bo = blockIdx.x >> 3, kz = blockIdx.x & 7;
    int t = threadIdx.x;
    __shared__ float2 in[256];   // [jx][jy]
    __shared__ float2 tw[64];
    if (t < 64) { float s, c; __sincosf(TWO_PI_OVER_64 * t, &s, &c); tw[t] = make_float2(c, s); }
    in[t] = S4[(size_t)bo * 2048 + (size_t)t * 8 + kz];
    __syncthreads();
    int x = t & 63, g = t >> 6;
    #pragma unroll
    for (int m = 0; m < 4; m++) {
        int jy = g + 4 * m;
        float re = 0.f, im = 0.f;
        #pragma unroll
        for (int jx = 0; jx < 16; jx++) {
            int f = jx < 8 ? jx : 48 + jx;
            float2 v = in[jx * 16 + jy];
            float2 w = tw[(f * x) & 63];
            re += v.x * w.x - v.y * w.y;   // e^{+i theta}
            im += v.x * w.y + v.y * w.x;
        }
        // S5 layout [bo][x][jy][kz]
        S5[((size_t)bo * 64 + x) * 128 + jy * 8 + kz] = make_float2(re, im);
    }
}

// ---------------- K5: fused inverse-y + inverse-z DFT + pointwise + add + gelu (IN-PLACE on X) ----
// block per (b, x, ygroup of 16): 1024 blocks, 256 threads
// Stage C uses ONLY named scalars (acc0..acc7, tz1..tz7) and a partially-unrolled c-loop.
// Evidence from r2..r7: any stage-C variant with a local ARRAY accumulator updated in a
// fully-unrolled loop generated GBs of scratch traffic (spilled accumulators); scalar-acc
// variants (r2/r6) ran clean. Named scalars cannot become an alloca; unroll 4 bounds the
// LDS-load scheduling window.
__global__ void __launch_bounds__(256, 3)
k_inv_yz_pw(const float2* __restrict__ S5, const float* __restrict__ w_pw,
            const float* __restrict__ b_pw, float* __restrict__ X,
            int layer, int do_gelu) {
    int blk = blockIdx.x;
    int yg = blk & 3, x = (blk >> 2) & 63, b = blk >> 8;
    int t = threadIdx.x;
    __shared__ float2 s5s[32 * 132];   // [o][jy*8+k], padded rows  33792 B
    __shared__ float2 st[256];         // [o][k]        2 KB
    __shared__ float xt[2048];         // [c][z]        8 KB
    __shared__ float wt[1024];         // w_pw [c][o]   4 KB
    __shared__ float bt[32];
    __shared__ float2 tw[64];
    if (t < 64) { float s, c; __sincosf(TWO_PI_OVER_64 * t, &s, &c); tw[t] = make_float2(c, s); }
    // stage s5s: coalesced float4 loads (per o: 128 contiguous float2), padded store
    #pragma unroll
    for (int i = 0; i < 8; i++) {
        int f4 = t + 256 * i;          // [0,2048): o*64 + j4
        int o = f4 >> 6, j4 = f4 & 63;
        float4 v = ((const float4*)(S5 + ((size_t)(b * 32 + o) * 64 + x) * 128))[j4];
        *(float4*)(&s5s[o * 132 + j4 * 2]) = v;
    }
    #pragma unroll
    for (int i = t; i < 1024; i += 256) wt[i] = w_pw[layer * 1024 + i];
    if (t < 32) bt[t] = b_pw[layer * 32 + t];
    __syncthreads();
    int z = t & 63, og = t >> 6;       // og is wave-uniform (wave = 64 lanes)
    int og8 = og * 8;
    // named z-twiddle registers (k=0 twiddle is (1,0): handled inline)
    float2 tz1 = tw[z];
    float2 tz2 = tw[(2 * z) & 63];
    float2 tz3 = tw[(3 * z) & 63];
    float2 tz4 = tw[(4 * z) & 63];
    float2 tz5 = tw[(5 * z) & 63];
    float2 tz6 = tw[(6 * z) & 63];
    float2 tz7 = tw[(7 * z) & 63];
    const float inv_n = 1.0f / 262144.0f;
    for (int yi = 0; yi < 16; yi++) {
        int y = yg * 16 + yi;
        // stage A: inverse-y for this y -> st[o][k]; padded s5s rows (conflict-free)
        {
            int o = t >> 3, k = t & 7;
            float re = 0.f, im = 0.f;
            #pragma unroll
            for (int jy = 0; jy < 16; jy++) {
                int f = jy < 8 ? jy : 48 + jy;
                float2 v = s5s[o * 132 + jy * 8 + k];
                float2 w = tw[(f * y) & 63];
                re += v.x * w.x - v.y * w.y;   // e^{+i theta}
                im += v.x * w.y + v.y * w.x;
            }
            st[t] = make_float2(re, im);
        }
        // stage B: load X column for this y
        size_t base = (size_t)b * 8388608 + (size_t)(x * 64 + y) * 64;
        #pragma unroll
        for (int i = 0; i < 8; i++) {
            int e = t + 256 * i;   // c*64 + z
            int c = e >> 6, zz = e & 63;
            xt[e] = X[base + (size_t)c * R3 + zz];
        }
        __syncthreads();
        // stage C init: inverse-z (pocketfft c2r: Re of k=0, 2x k=1..7); st reads are
        // wave-uniform b64 broadcasts (og wave-uniform). All values named scalars.
#define INVZ_S(o) (st[(o) * 8 + 0].x \
        + 2.f * (st[(o) * 8 + 1].x * tz1.x - st[(o) * 8 + 1].y * tz1.y) \
        + 2.f * (st[(o) * 8 + 2].x * tz2.x - st[(o) * 8 + 2].y * tz2.y) \
        + 2.f * (st[(o) * 8 + 3].x * tz3.x - st[(o) * 8 + 3].y * tz3.y) \
        + 2.f * (st[(o) * 8 + 4].x * tz4.x - st[(o) * 8 + 4].y * tz4.y) \
        + 2.f * (st[(o) * 8 + 5].x * tz5.x - st[(o) * 8 + 5].y * tz5.y) \
        + 2.f * (st[(o) * 8 + 6].x * tz6.x - st[(o) * 8 + 6].y * tz6.y) \
        + 2.f * (st[(o) * 8 + 7].x * tz7.x - st[(o) * 8 + 7].y * tz7.y))
        float acc0 = bt[og8 + 0] + INVZ_S(og8 + 0) * inv_n;
        float acc1 = bt[og8 + 1] + INVZ_S(og8 + 1) * inv_n;
        float acc2 = bt[og8 + 2] + INVZ_S(og8 + 2) * inv_n;
        float acc3 = bt[og8 + 3] + INVZ_S(og8 + 3) * inv_n;
        float acc4 = bt[og8 + 4] + INVZ_S(og8 + 4) * inv_n;
        float acc5 = bt[og8 + 5] + INVZ_S(og8 + 5) * inv_n;
        float acc6 = bt[og8 + 6] + INVZ_S(og8 + 6) * inv_n;
        float acc7 = bt[og8 + 7] + INVZ_S(og8 + 7) * inv_n;
#undef INVZ_S
        // stage C main: c-outer pointwise; xt once per c, wt as two b128 broadcasts.
        // unroll 4 keeps the LDS-load scheduling window small (no spill pressure).
        #pragma unroll 4
        for (int c = 0; c < 32; c++) {
            float xc = xt[c * 64 + z];
            float4 wA = *(const float4*)(wt + c * 32 + og8);       // broadcast
            float4 wB = *(const float4*)(wt + c * 32 + og8 + 4);   // broadcast
            acc0 += xc * wA.x; acc1 += xc * wA.y; acc2 += xc * wA.z; acc3 += xc * wA.w;
            acc4 += xc * wB.x; acc5 += xc * wB.y; acc6 += xc * wB.z; acc7 += xc * wB.w;
        }
        __syncthreads();   // all st/xt reads done before next iteration overwrites
        float r;
        r = do_gelu ? geluf(acc0) : acc0; X[base + (size_t)(og8 + 0) * R3 + z] = r;
        r = do_gelu ? geluf(acc1) : acc1; X[base + (size_t)(og8 + 1) * R3 + z] = r;
        r = do_gelu ? geluf(acc2) : acc2; X[base + (size_t)(og8 + 2) * R3 + z] = r;
        r = do_gelu ? geluf(acc3) : acc3; X[base + (size_t)(og8 + 3) * R3 + z] = r;
        r = do_gelu ? geluf(acc4) : acc4; X[base + (size_t)(og8 + 4) * R3 + z] = r;
        r = do_gelu ? geluf(acc5) : acc5; X[base + (size_t)(og8 + 5) * R3 + z] = r;
        r = do_gelu ? geluf(acc6) : acc6; X[base + (size_t)(og8 + 6) * R3 + z] = r;
        r = do_gelu ? geluf(acc7) : acc7; X[base + (size_t)(og8 + 7) * R3 + z] = r;
    }
}

// ---------------- K6: head fc1(32->128) + gelu + fc2(128->6), scalar-pipe weights ----------------
// 4096 blocks, 256 threads, one site each
__global__ void k_head(const float* __restrict__ X, const float* __restrict__ w1,
                       const float* __restrict__ b1, const float* __restrict__ w2,
                       const float* __restrict__ b2, float* __restrict__ tau_out) {
    int t = threadIdx.x;
    size_t s = (size_t)blockIdx.x * 256 + t;
    int b = (int)(s >> 18);
    size_t p = s & (R3 - 1);
    float xr[32];
    const float* xb = X + (size_t)b * 8388608 + p;
    #pragma unroll
    for (int c = 0; c < 32; c++) xr[c] = xb[(size_t)c * R3];
    float acc[6];
    #pragma unroll
    for (int o = 0; o < 6; o++) acc[o] = b2[o];
    for (int h = 0; h < 128; h += 4) {
        float a0 = b1[h], a1 = b1[h + 1], a2 = b1[h + 2], a3 = b1[h + 3];
        #pragma unroll
        for (int c = 0; c < 32; c++) {
            float xv = xr[c];
            const float* wr = w1 + c * 128 + h;   // uniform: s_load_dwordx4
            a0 += xv * wr[0];
            a1 += xv * wr[1];
            a2 += xv * wr[2];
            a3 += xv * wr[3];
        }
        a0 = geluf(a0); a1 = geluf(a1); a2 = geluf(a2); a3 = geluf(a3);
        const float* w2r = w2 + h * 6;            // uniform: 24 contiguous floats
        #pragma unroll
        for (int o = 0; o < 6; o++) {
            acc[o] += a0 * w2r[o] + a1 * w2r[6 + o] + a2 * w2r[12 + o] + a3 * w2r[18 + o];
        }
    }
    float* ob = tau_out + (size_t)b * 6 * R3 + p;
    #pragma unroll
    for (int o = 0; o < 6; o++) ob[(size_t)o * R3] = acc[o];
}

// ---------------- K7: NS hard core + combine ----------------
// 12288 blocks, 256 threads; s over B*3*R3
__global__ void k_hard(const float* __restrict__ u, const float* __restrict__ tau,
                       float* __restrict__ out0) {
    size_t s = (size_t)blockIdx.x * 256 + threadIdx.x;
    int bi = (int)(s >> 18);
    int b = bi / 3, i = bi % 3;
    size_t p = s & (R3 - 1);
    int x = (int)(p >> 12), y = ((int)p >> 6) & 63, z = (int)p & 63;
    const float dx = TWO_PI_OVER_64;
    const float inv2dx = 1.0f / (2.0f * dx);
    const float invdx2 = 1.0f / (dx * dx);
    const float* ub = u + (size_t)b * 3 * R3;
    const float* ui = ub + (size_t)i * R3;
    int xp = (x + 1) & 63, xm = (x + 63) & 63;
    int yp = (y + 1) & 63, ym = (y + 63) & 63;
    int zp = (z + 1) & 63, zm = (z + 63) & 63;
    float c0 = ui[p];
    float upx = ui[((size_t)xp << 12) | (y << 6) | z], umx = ui[((size_t)xm << 12) | (y << 6) | z];
    float upy = ui[((size_t)x << 12) | (yp << 6) | z], umy = ui[((size_t)x << 12) | (ym << 6) | z];
    float upz = ui[((size_t)x << 12) | (y << 6) | zp], umz = ui[((size_t)x << 12) | (y << 6) | zm];
    float u0c = ub[p], u1c = ub[R3 + p], u2c = ub[2 * R3 + p];
    float conv = -(u0c * (upx - umx) + u1c * (upy - umy) + u2c * (upz - umz)) * inv2dx;
    float diff = (upx + umx + upy + umy + upz + umz - 6.0f * c0) * invdx2;
    float tauv = tau[(size_t)b * 6 * R3 + (size_t)i * R3 + p];
    out0[s] = conv + 0.000185f * diff + 0.001f * tauv;
}

extern "C" void kernel_launch(void* const* d_in, const int* in_sizes, int n_in,
                              void* d_out, int out_size, void* d_ws, size_t ws_size,
                              hipStream_t stream) {
    const float* u      = (const float*)d_in[0];
    const float* fc0_w  = (const float*)d_in[1];
    const float* fc0_b  = (const float*)d_in[2];
    const float* spec_w = (const float*)d_in[3];
    const float* w_pw   = (const float*)d_in[4];
    const float* b_pw   = (const float*)d_in[5];
    const float* fc1_w  = (const float*)d_in[6];
    const float* fc1_b  = (const float*)d_in[7];
    const float* fc2_w  = (const float*)d_in[8];
    const float* fc2_b  = (const float*)d_in[9];
    float* out = (float*)d_out;

    // d_ws: only the activation tensor X (B*32*64^3 floats = 128 MiB), updated in place.
    float* X = (float*)d_ws;

    // Spectral stage buffers live in d_out's dead space (20 MiB of 36 MiB total).
    // All are dead before k_head/k_hard overwrite tau/du at the end.
    float2* S2 = (float2*)(out);                // 1048576 float2 =  8 MiB, floats [0, 2097152)
    float2* S3 = (float2*)(out + 2097152);      //  262144 float2 =  2 MiB
    float2* S4 = (float2*)(out + 2621440);      //  262144 float2 =  2 MiB
    float2* S5 = (float2*)(out + 3145728);      // 1048576 float2 =  8 MiB, ends at float 5242880

    k_fc0<<<4096, 256, 0, stream>>>(u, fc0_w, fc0_b, X);

    for (int l = 0; l < 4; l++) {
        k_fwd_zy<<<8192, 256, 0, stream>>>(X, S2);
        k_fwd_x<<<1024, 256, 0, stream>>>(S2, S3);
        k_specmul<<<1024, 128, 0, stream>>>(S3, spec_w, S4, l);
        k_inv_x<<<1024, 256, 0, stream>>>(S4, S5);
        k_inv_yz_pw<<<1024, 256, 0, stream>>>(S5, w_pw, b_pw, X, l, (l < 3) ? 1 : 0);
    }

    float* tau_out = out + (size_t)4 * 3 * R3;   // second output section (offset 3145728)
    k_head<<<4096, 256, 0, stream>>>(X, fc1_w, fc1_b, fc2_w, fc2_b, tau_out);
    k_hard<<<12288, 256, 0, stream>>>(u, tau_out, out);
}